// Round 9
// baseline (132.328 us; speedup 1.0000x reference)
//
#include <hip/hip_runtime.h>
#include <hip/hip_bf16.h>
#include <stdint.h>

#define UNITS 1024
#define IDIM  512
#define BATCH 2048
#define KTOT  1536   // UNITS + IDIM
#define NGATE 4096   // 4*UNITS
#define NKK   48     // KTOT / 32 k-chunks; 1 kk per K-iter

typedef short bf16x8 __attribute__((ext_vector_type(8)));   // 8 bf16 = 4 VGPRs
typedef float f32x4  __attribute__((ext_vector_type(4)));

union P8 { bf16x8 v; __hip_bfloat16 e[8]; };

// Fragment-ordered layouts (R7-proven):
//   A2: frag(ii,kk) at [(ii*NKK + kk)*64 + L]*16B ; lane L holds
//       A[ii*16 + (L&15)][kk*32 + (L>>4)*8 .. +8]
//   Wt2: frag(jj,kk) likewise (jj = W^T row/16, 256 total).
// Every fragment = 1KB contiguous -> one coalesced dwordx4 per lane.

#define NBLK_A 1536
#define NBLK_T 3072

__global__ __launch_bounds__(256) void prep(
    const float* __restrict__ x, const float* __restrict__ h,
    const float* __restrict__ W,
    bf16x8* __restrict__ A2, bf16x8* __restrict__ Wt2) {
  __shared__ float tile[32][65];
  const int tid = threadIdx.x;
  if (blockIdx.x < NBLK_A) {
    const int gid = blockIdx.x * 256 + tid;
    const int f  = gid >> 6;                  // fragment 0..6143
    const int L  = gid & 63;
    const int ii = f / NKK;
    const int kk = f - ii * NKK;
    const int r  = ii * 16 + (L & 15);
    const int k  = kk * 32 + (L >> 4) * 8;
    const float* src = (k < UNITS) ? h + (size_t)r * UNITS + k
                                   : x + (size_t)r * IDIM + (k - UNITS);
    const float4 v0 = ((const float4*)src)[0];
    const float4 v1 = ((const float4*)src)[1];
    P8 o;
    o.e[0] = __float2bfloat16(v0.x); o.e[1] = __float2bfloat16(v0.y);
    o.e[2] = __float2bfloat16(v0.z); o.e[3] = __float2bfloat16(v0.w);
    o.e[4] = __float2bfloat16(v1.x); o.e[5] = __float2bfloat16(v1.y);
    o.e[6] = __float2bfloat16(v1.z); o.e[7] = __float2bfloat16(v1.w);
    A2[gid] = o.v;
  } else {
    const int b  = blockIdx.x - NBLK_A;   // 0..3071
    const int kb = b >> 7;                // 0..23
    const int nb = b & 127;               // 0..127
    const int k0 = kb * 64, n0 = nb * 32;
    const int n4 = (tid & 7) * 4;
    const int kk = tid >> 3;              // 0..31
#pragma unroll
    for (int rr = 0; rr < 64; rr += 32) {
      const float4 v = *(const float4*)(W + (size_t)(k0 + kk + rr) * NGATE + n0 + n4);
      tile[n4 + 0][kk + rr] = v.x; tile[n4 + 1][kk + rr] = v.y;
      tile[n4 + 2][kk + rr] = v.z; tile[n4 + 3][kk + rr] = v.w;
    }
    __syncthreads();
    const int L    = tid & 63;
    const int half = tid >> 6;
    const int jl   = half >> 1;
    const int kl   = half & 1;
    const int nloc = (L & 15) + jl * 16;
    const int kloc = kl * 32 + (L >> 4) * 8;
    P8 o;
#pragma unroll
    for (int j = 0; j < 8; ++j) o.e[j] = __float2bfloat16(tile[nloc][kloc + j]);
    const int jj = (n0 >> 4) + jl;
    const int kc = (k0 >> 5) + kl;
    Wt2[(size_t)(jj * NKK + kc) * 64 + L] = o.v;
  }
}

// ---------------------------------------------------------------------------
// R9 GEMM: DEPTH-4 register pipeline, no LDS, no barriers.
// R4-R8 post-mortem: five distinct structures all pinned at ~43us because
// every one had prefetch depth 1 (one iter of compute ~650cyc vs operand
// latency ~600-1800cyc -> structural stall). Here the K-step is 1 kk
// (32 k, 48 iters; 8 fragment loads + 16 MFMA per iter) and fragments live
// in an explicit 4-slot rolling FIFO: while computing iter `it`, the loads
// for it+3 are issued -> ~24 loads (24KB) outstanding per wave, ~3 iters
// (~2000cyc) of latency cover. VGPR-dest loads let the compiler emit
// partial vmcnt(N) waits (impossible with global_load_lds + barrier).
// Tile: grid 512, block 128 rows x 32 units x 4 gates, waves 2x2,
// wave 64x64, acc[4][4] (64 VGPR) + FIFO 128 VGPR + cpre 16 ~= 230.
// L1 dedups the 2-wave sharing of each frag. XCD: bi%8 = ub%8.
// ---------------------------------------------------------------------------
__global__ __launch_bounds__(256, 2) void lstm_gemm(
    const bf16x8* __restrict__ A2,
    const bf16x8* __restrict__ Wt2,
    const float* __restrict__ c_tm1,
    float* __restrict__ out) {
  const int tid  = threadIdx.x;
  const int w    = tid >> 6;     // wave 0..3 (uniform)
  const int lane = tid & 63;
  const int quad = lane >> 4;
  const int m16  = lane & 15;
  const int wr   = w >> 1;       // row half (0,1)
  const int wu   = w & 1;        // unit half (0,1)

  const int mb = blockIdx.x >> 5;   // 0..15
  const int ub = blockIdx.x & 31;   // 0..31  (XCD = bi%8 = ub%8)
  const int m0 = mb * 128;
  const int u0 = ub * 32;

  // fragment base offsets (16B units); step per kk = 64
  size_t aoff[4], boff[4];
  const int ii0 = mb * 8 + wr * 4;
#pragma unroll
  for (int i = 0; i < 4; ++i)
    aoff[i] = (size_t)((ii0 + i) * NKK) * 64 + lane;
#pragma unroll
  for (int g = 0; g < 4; ++g) {
    const int jj = g * 64 + ub * 2 + wu;
    boff[g] = (size_t)(jj * NKK) * 64 + lane;
  }

  // preload c_tm1 (epilogue-only; hides its HBM latency behind the K-loop)
  const int u = u0 + wu * 16 + m16;
  float cpre[16];
#pragma unroll
  for (int i = 0; i < 4; ++i)
#pragma unroll
    for (int reg = 0; reg < 4; ++reg) {
      const int r = m0 + wr * 64 + i * 16 + quad * 4 + reg;
      cpre[i * 4 + reg] = c_tm1[(size_t)r * UNITS + u];
    }

  f32x4 acc[4][4];
#pragma unroll
  for (int i = 0; i < 4; ++i)
#pragma unroll
    for (int g = 0; g < 4; ++g) {
      f32x4 z = {0.f, 0.f, 0.f, 0.f};
      acc[i][g] = z;
    }

  bf16x8 a[4][4], b[4][4];   // [slot][i|g] rolling FIFO, depth 4

  // prologue: fill slots 0..2 (kk = 0,1,2)
#pragma unroll
  for (int s = 0; s < 3; ++s) {
#pragma unroll
    for (int i = 0; i < 4; ++i) a[s][i] = A2[aoff[i] + (size_t)s * 64];
#pragma unroll
    for (int g = 0; g < 4; ++g) b[s][g] = Wt2[boff[g] + (size_t)s * 64];
  }

#pragma unroll 4
  for (int it = 0; it < NKK; ++it) {
    const int slot = it & 3;
    // issue loads for it+3 into slot (it+3)&3 BEFORE computing `it`
    if (it < NKK - 3) {
      const int ns = (it + 3) & 3;
      const size_t ko = (size_t)(it + 3) * 64;
#pragma unroll
      for (int i = 0; i < 4; ++i) a[ns][i] = A2[aoff[i] + ko];
#pragma unroll
      for (int g = 0; g < 4; ++g) b[ns][g] = Wt2[boff[g] + ko];
    }
#pragma unroll
    for (int g = 0; g < 4; ++g)
#pragma unroll
      for (int i = 0; i < 4; ++i)
        acc[i][g] = __builtin_amdgcn_mfma_f32_16x16x32_bf16(a[slot][i], b[slot][g],
                                                            acc[i][g], 0, 0, 0);
  }

  // fused LSTM epilogue -- all 4 gates in-lane
#pragma unroll
  for (int i = 0; i < 4; ++i)
#pragma unroll
    for (int reg = 0; reg < 4; ++reg) {
      const int r = m0 + wr * 64 + i * 16 + quad * 4 + reg;
      const float z0 = acc[i][0][reg];   // gate i
      const float z1 = acc[i][1][reg];   // gate f
      const float z2 = acc[i][2][reg];   // c_tilde
      const float z3 = acc[i][3][reg];   // gate o
      const float ig = 1.f / (1.f + __expf(-z0));
      const float fg = 1.f / (1.f + __expf(-z1));
      const float ct = 1.f - 2.f / (__expf(2.f * z2) + 1.f);   // tanh, inf-safe
      const float og = 1.f / (1.f + __expf(-z3));
      const float cc = fg * cpre[i * 4 + reg] + ig * ct;
      const float hh = og * (1.f - 2.f / (__expf(2.f * cc) + 1.f));
      out[(size_t)r * UNITS + u] = hh;
      out[(size_t)BATCH * UNITS + (size_t)r * UNITS + u] = cc;
    }
}

// ---------------------------------------------------------------------------
// Fallback (only if d_ws too small): naive fp32, correct but slow.
// ---------------------------------------------------------------------------
__global__ __launch_bounds__(256) void lstm_naive(
    const float* __restrict__ x, const float* __restrict__ h,
    const float* __restrict__ c_tm1, const float* __restrict__ W,
    float* __restrict__ out) {
  int idx = blockIdx.x * 256 + threadIdx.x;
  int r = idx / UNITS;
  int u = idx % UNITS;
  float z[4] = {0.f, 0.f, 0.f, 0.f};
  for (int k = 0; k < KTOT; ++k) {
    float a = (k < UNITS) ? h[(size_t)r * UNITS + k] : x[(size_t)r * IDIM + k - UNITS];
#pragma unroll
    for (int g = 0; g < 4; ++g)
      z[g] += a * W[(size_t)k * NGATE + g * UNITS + u];
  }
  float ig = 1.f / (1.f + __expf(-z[0]));
  float fg = 1.f / (1.f + __expf(-z[1]));
  float ct = 1.f - 2.f / (__expf(2.f * z[2]) + 1.f);
  float og = 1.f / (1.f + __expf(-z[3]));
  float cc = fg * c_tm1[(size_t)r * UNITS + u] + ig * ct;
  float hh = og * (1.f - 2.f / (__expf(2.f * cc) + 1.f));
  out[(size_t)r * UNITS + u] = hh;
  out[(size_t)BATCH * UNITS + (size_t)r * UNITS + u] = cc;
}

extern "C" void kernel_launch(void* const* d_in, const int* in_sizes, int n_in,
                              void* d_out, int out_size, void* d_ws, size_t ws_size,
                              hipStream_t stream) {
  const float* x = (const float*)d_in[0];   // [2048][512]
  const float* h = (const float*)d_in[1];   // [2048][1024]
  const float* c = (const float*)d_in[2];   // [2048][1024]
  const float* W = (const float*)d_in[3];   // [1536][4096]
  float* out = (float*)d_out;               // h then c, 2 x [2048][1024]

  const size_t needA  = (size_t)BATCH * KTOT * sizeof(__hip_bfloat16);  // 6.29 MB
  const size_t needWt = (size_t)NGATE * KTOT * sizeof(__hip_bfloat16);  // 12.58 MB
  if (ws_size < needA + needWt) {
    hipLaunchKernelGGL(lstm_naive, dim3((BATCH * UNITS) / 256), dim3(256), 0, stream,
                       x, h, c, W, out);
    return;
  }

  bf16x8* A2  = (bf16x8*)d_ws;
  bf16x8* Wt2 = (bf16x8*)((char*)d_ws + needA);

  hipLaunchKernelGGL(prep, dim3(NBLK_A + NBLK_T), dim3(256), 0, stream, x, h, W, A2, Wt2);
  hipLaunchKernelGGL(lstm_gemm, dim3(512), dim3(256), 0, stream, A2, Wt2, c, out);
}